// Round 1
// baseline (91.386 us; speedup 1.0000x reference)
//
#include <hip/hip_runtime.h>
#include <hip/hip_bf16.h>

typedef __attribute__((ext_vector_type(4))) float f32x4;
typedef __attribute__((ext_vector_type(8))) short bf16x8;
typedef __attribute__((ext_vector_type(4))) unsigned short u16x4;

#define NH 8
#define HD 64
#define WSZ 128
#define DM 512

__device__ __forceinline__ unsigned short f2bf(float f) {
    unsigned int u = __float_as_uint(f);
    u += 0x7fffu + ((u >> 16) & 1u);
    return (unsigned short)(u >> 16);
}

// One block = one (batch, window, head). 4 waves, each owns 32 query rows.
__global__ __launch_bounds__(256, 2) void wattn_kernel(
    const float* __restrict__ q1, const float* __restrict__ k1,
    const float* __restrict__ v1, float* __restrict__ o1, int nw1,
    const float* __restrict__ q2, const float* __restrict__ k2,
    const float* __restrict__ v2, float* __restrict__ o2, int nw2,
    int nblk1)
{
    // K tile bf16 row-major, d padded 64->72 (row 144B -> 2-way-free frag reads)
    __shared__ __align__(16) unsigned short Kl[128][72];
    // V^T tile bf16: Vt[d][k ^ (((d>>1)&7)<<3)]  (XOR on aligned 8-blocks of k)
    __shared__ __align__(16) unsigned short Vt[64][128];
    // per-wave P chunk (32 q rows x 32 k), row padded to 40
    __shared__ __align__(16) unsigned short Pl[4][32][40];

    const int t = threadIdx.x;
    const int lane = t & 63;
    const int wid = t >> 6;
    const int g = lane >> 4;    // 0..3
    const int c = lane & 15;    // 0..15

    int bid = blockIdx.x;
    const float *q, *k, *v; float* o; int nw;
    if (bid < nblk1) { q = q1; k = k1; v = v1; o = o1; nw = nw1; }
    else { bid -= nblk1; q = q2; k = k2; v = v2; o = o2; nw = nw2; }

    const int h = bid & (NH - 1);
    const int w = (bid / NH) % nw;
    const int b = bid / (NH * nw);

    const size_t row0 = ((size_t)b * nw + w) * WSZ;   // first token row of window
    const float* Qp = q + row0 * DM + h * HD;
    const float* Kp = k + row0 * DM + h * HD;
    const float* Vp = v + row0 * DM + h * HD;
    float* Op = o + row0 * DM + h * HD;

    // ---- stage K (row-major bf16) and V (transposed + swizzled bf16) ----
#pragma unroll
    for (int i = 0; i < 8; ++i) {
        int e = (i * 256 + t) * 4;          // element in 128x64 tile
        int kr = e >> 6;
        int dc = e & 63;
        f32x4 kv = *reinterpret_cast<const f32x4*>(Kp + (size_t)kr * DM + dc);
        u16x4 kb;
        kb[0] = f2bf(kv[0]); kb[1] = f2bf(kv[1]);
        kb[2] = f2bf(kv[2]); kb[3] = f2bf(kv[3]);
        *reinterpret_cast<u16x4*>(&Kl[kr][dc]) = kb;

        f32x4 vv = *reinterpret_cast<const f32x4*>(Vp + (size_t)kr * DM + dc);
#pragma unroll
        for (int j = 0; j < 4; ++j) {
            int d = dc + j;
            int xk = kr ^ (((d >> 1) & 7) << 3);
            Vt[d][xk] = f2bf(vv[j]);
        }
    }

    // ---- Q fragments straight from global (each element read exactly once) ----
    const int qrow0 = wid * 32;
    bf16x8 qf[2][2];
#pragma unroll
    for (int m = 0; m < 2; ++m) {
#pragma unroll
        for (int ks = 0; ks < 2; ++ks) {
            const float* src = Qp + (size_t)(qrow0 + m * 16 + c) * DM + ks * 32 + g * 8;
            f32x4 a = *reinterpret_cast<const f32x4*>(src);
            f32x4 bq = *reinterpret_cast<const f32x4*>(src + 4);
            bf16x8 f;
            f[0] = (short)f2bf(a[0]);  f[1] = (short)f2bf(a[1]);
            f[2] = (short)f2bf(a[2]);  f[3] = (short)f2bf(a[3]);
            f[4] = (short)f2bf(bq[0]); f[5] = (short)f2bf(bq[1]);
            f[6] = (short)f2bf(bq[2]); f[7] = (short)f2bf(bq[3]);
            qf[m][ks] = f;
        }
    }

    __syncthreads();

    // ---- S = Q K^T : acc[m][n], D layout col=lane&15 (k idx), row=g*4+r (q idx)
    f32x4 acc[2][8] = {};
#pragma unroll
    for (int ks = 0; ks < 2; ++ks) {
#pragma unroll
        for (int n = 0; n < 8; ++n) {
            bf16x8 kf = *reinterpret_cast<const bf16x8*>(&Kl[n * 16 + c][ks * 32 + g * 8]);
            acc[0][n] = __builtin_amdgcn_mfma_f32_16x16x32_bf16(qf[0][ks], kf, acc[0][n], 0, 0, 0);
            acc[1][n] = __builtin_amdgcn_mfma_f32_16x16x32_bf16(qf[1][ks], kf, acc[1][n], 0, 0, 0);
        }
    }

    // ---- softmax over k (cols). Row q owned by 16 lanes sharing g. ----
    float rinv[2][4];
#pragma unroll
    for (int m = 0; m < 2; ++m) {
#pragma unroll
        for (int r = 0; r < 4; ++r) {
            float mx = acc[m][0][r];
#pragma unroll
            for (int n = 1; n < 8; ++n) mx = fmaxf(mx, acc[m][n][r]);
#pragma unroll
            for (int off = 1; off < 16; off <<= 1) mx = fmaxf(mx, __shfl_xor(mx, off));
            float s = 0.f;
#pragma unroll
            for (int n = 0; n < 8; ++n) {
                float p = __expf(0.125f * (acc[m][n][r] - mx));
                acc[m][n][r] = p;
                s += p;
            }
#pragma unroll
            for (int off = 1; off < 16; off <<= 1) s += __shfl_xor(s, off);
            rinv[m][r] = 1.0f / s;
        }
    }

    // ---- O = P V, k in 4 chunks of 32 through per-wave Pl (no barriers) ----
    f32x4 oacc[2][4] = {};
#pragma unroll
    for (int ck = 0; ck < 4; ++ck) {
#pragma unroll
        for (int m = 0; m < 2; ++m) {
#pragma unroll
            for (int nn = 0; nn < 2; ++nn) {
#pragma unroll
                for (int r = 0; r < 4; ++r) {
                    float p = acc[m][ck * 2 + nn][r] * rinv[m][r];
                    Pl[wid][m * 16 + g * 4 + r][nn * 16 + c] = f2bf(p);
                }
            }
        }
        bf16x8 pf0 = *reinterpret_cast<const bf16x8*>(&Pl[wid][c][g * 8]);
        bf16x8 pf1 = *reinterpret_cast<const bf16x8*>(&Pl[wid][16 + c][g * 8]);
#pragma unroll
        for (int n = 0; n < 4; ++n) {
            int d = n * 16 + c;
            int xk = (ck * 32 + g * 8) ^ (((d >> 1) & 7) << 3);
            bf16x8 vf = *reinterpret_cast<const bf16x8*>(&Vt[d][xk]);
            oacc[0][n] = __builtin_amdgcn_mfma_f32_16x16x32_bf16(pf0, vf, oacc[0][n], 0, 0, 0);
            oacc[1][n] = __builtin_amdgcn_mfma_f32_16x16x32_bf16(pf1, vf, oacc[1][n], 0, 0, 0);
        }
    }

    // ---- store O (fp32), lanes 0..15 contiguous in d ----
#pragma unroll
    for (int m = 0; m < 2; ++m) {
#pragma unroll
        for (int n = 0; n < 4; ++n) {
#pragma unroll
            for (int r = 0; r < 4; ++r) {
                int row = qrow0 + m * 16 + g * 4 + r;
                Op[(size_t)row * DM + n * 16 + c] = oacc[m][n][r];
            }
        }
    }
}

extern "C" void kernel_launch(void* const* d_in, const int* in_sizes, int n_in,
                              void* d_out, int out_size, void* d_ws, size_t ws_size,
                              hipStream_t stream) {
    const float* q1 = (const float*)d_in[0];
    const float* k1 = (const float*)d_in[1];
    const float* v1 = (const float*)d_in[2];
    const float* q2 = (const float*)d_in[3];
    const float* k2 = (const float*)d_in[4];
    const float* v2 = (const float*)d_in[5];

    // B=8 per the reference setup
    const int B = 8;
    const int nw1 = in_sizes[0] / (B * DM * WSZ);   // 32
    const int nw2 = in_sizes[3] / (B * DM * WSZ);   // 16

    float* o1 = (float*)d_out;
    float* o2 = o1 + (size_t)in_sizes[0];

    const int nblk1 = B * nw1 * NH;                 // 2048
    const int nblk2 = B * nw2 * NH;                 // 1024

    wattn_kernel<<<dim3(nblk1 + nblk2), dim3(256), 0, stream>>>(
        q1, k1, v1, o1, nw1, q2, k2, v2, o2, nw2, nblk1);
}